// Round 17
// baseline (194.006 us; speedup 1.0000x reference)
//
#include <hip/hip_runtime.h>
#include <math.h>

#define N_EDGES     1048576
#define NBKT        4096         // bucket = seg >> 5 (32 segs / bucket)
#define SEG_PER_BKT 32
#define N_BASIS     12
#define CAP         344          // per-bucket capacity (Poisson(256)+5.5sd; slow path kept)
#define PAY_SZ      (CAP * 7 + CAP / 8)   // j-padded: slot(j) = 7j + (j>>3)
#define HBLK        256          // hist/partition blocks (256 threads each)
#define HEPB        (N_EDGES / HBLK)   // 4096 edges per block

// rec = (sl << 20) | eid   (sl = seg & 31, eid < 2^20)

// ---- workspace layout (8.03 MB) ----
#define WS_BLKHIST  0                          // int[HBLK][NBKT]  (4 MB)
#define WS_TOTALS   (HBLK * NBKT * 4)          // int[NBKT] (16 KB)
#define WS_OFFSETS  (WS_TOTALS + NBKT * 4)     // int[NBKT] (16 KB)
#define WS_REC      (WS_OFFSETS + NBKT * 4)    // u32[N_EDGES] (4 MB)
#define WS_NEED     (WS_REC + (size_t)N_EDGES * 4)

__device__ __forceinline__ int pslot(int j) { return j * 7 + (j >> 3); }

__device__ __forceinline__ void compute_edge(float x, float y, float z,
                                             float* __restrict__ ph,   // 12, scaled by NORM/r
                                             float* __restrict__ sh)   // 16
{
    const float r2    = fmaf(x, x, fmaf(y, y, z * z)) + 1e-12f;
    const float inv_r = rsqrtf(r2);
    const float r     = r2 * inv_r;
    x *= inv_r; y *= inv_r; z *= inv_r;

    const float t = 0.6283185307179586f * r;   // pi/5 * r
    float s1, c1;
    __sincosf(t, &s1, &c1);
    const float twoc = 2.0f * c1;
    const float scale = 0.17677669529663687f * inv_r;  // (1/sqrt(32)) / r
    float skm1 = 0.0f, sk = s1;
    #pragma unroll
    for (int b = 0; b < N_BASIS; ++b) {
        ph[b] = sk * scale;
        const float nxt = fmaf(twoc, sk, -skm1);
        skm1 = sk; sk = nxt;
    }

    const float x2 = x * x, y2 = y * y, z2 = z * z;
    sh[0]  = 0.28209479177387814f;
    sh[1]  = 0.4886025119029199f * y;
    sh[2]  = 0.4886025119029199f * z;
    sh[3]  = 0.4886025119029199f * x;
    sh[4]  = 1.0925484305920792f * x * y;
    sh[5]  = 1.0925484305920792f * y * z;
    sh[6]  = 0.31539156525252005f * (3.0f * z2 - 1.0f);
    sh[7]  = 1.0925484305920792f * x * z;
    sh[8]  = 0.5462742152960396f * (x2 - y2);
    sh[9]  = 0.5900435899266435f * y * (3.0f * x2 - y2);
    sh[10] = 2.890611442640554f  * x * y * z;
    sh[11] = 0.4570457994644658f * y * (5.0f * z2 - 1.0f);
    sh[12] = 0.3731763325901154f * (5.0f * z2 * z - 3.0f * z);
    sh[13] = 0.4570457994644658f * x * (5.0f * z2 - 1.0f);
    sh[14] = 1.445305721320277f  * z * (x2 - y2);
    sh[15] = 0.5900435899266435f * x * (x2 - y2);
}

// ---------- 1: per-block histogram (LDS only; coalesced writeout) ----------
__global__ __launch_bounds__(256) void hist_kernel(
    const int* __restrict__ cidx, const int* __restrict__ sidx,
    int* __restrict__ blkhist)
{
    __shared__ int h[NBKT];                    // 16 KB
    const int t = threadIdx.x;
    #pragma unroll
    for (int i = t; i < NBKT; i += 256) h[i] = 0;
    __syncthreads();
    const int base = blockIdx.x * HEPB;
    #pragma unroll
    for (int k = 0; k < HEPB / 256; ++k) {
        const int e = base + k * 256 + t;
        const int seg = (cidx[e] << 2) | sidx[e];
        atomicAdd(&h[seg >> 5], 1);
    }
    __syncthreads();
    #pragma unroll
    for (int i = t; i < NBKT; i += 256)
        blkhist[blockIdx.x * NBKT + i] = h[i];
}

// ---------- 2: per-bucket exclusive scan over the 256 hist rows (in-place) ----------
__global__ __launch_bounds__(128) void scanA_kernel(
    int* __restrict__ blkhist, int* __restrict__ totals)
{
    const int bkt = blockIdx.x * 128 + threadIdx.x;   // 4096 threads, 32 blocks
    int run = 0;
    for (int blk = 0; blk < HBLK; ++blk) {
        const int v = blkhist[blk * NBKT + bkt];      // coalesced per row
        blkhist[blk * NBKT + bkt] = run;              // exclusive within bucket
        run += v;
    }
    totals[bkt] = run;
}

// ---------- 3: exclusive scan of 4096 bucket totals (1 block, int4 ladder) ----------
__global__ __launch_bounds__(1024) void scanB_kernel(
    const int* __restrict__ totals, int* __restrict__ offsets)
{
    __shared__ int tmp[1024];
    const int t = threadIdx.x;
    const int4 tv = ((const int4*)totals)[t];
    const int a0 = tv.x, a1 = a0 + tv.y, a2 = a1 + tv.z, a3 = a2 + tv.w;
    tmp[t] = a3;
    __syncthreads();
    #pragma unroll
    for (int d = 1; d < 1024; d <<= 1) {
        const int v = (t >= d) ? tmp[t - d] : 0;
        __syncthreads();
        tmp[t] += v;
        __syncthreads();
    }
    const int ex = tmp[t] - a3;                       // exclusive over quads
    offsets[4 * t + 0] = ex;
    offsets[4 * t + 1] = ex + a0;
    offsets[4 * t + 2] = ex + a1;
    offsets[4 * t + 3] = ex + a2;
}

// ---------- 4: partition (deterministic bases; LDS rank; 4B stores) ----------
__global__ __launch_bounds__(256) void partition_kernel(
    const int* __restrict__ cidx, const int* __restrict__ sidx,
    const int* __restrict__ blkhist, const int* __restrict__ offsets,
    unsigned int* __restrict__ records)
{
    __shared__ int bb[NBKT];                   // 16 KB
    __shared__ int lcnt[NBKT];                 // 16 KB
    const int t = threadIdx.x;
    #pragma unroll
    for (int i = t; i < NBKT; i += 256) {
        bb[i] = offsets[i] + blkhist[blockIdx.x * NBKT + i];
        lcnt[i] = 0;
    }
    __syncthreads();
    const int base = blockIdx.x * HEPB;
    #pragma unroll
    for (int k = 0; k < HEPB / 256; ++k) {
        const int e = base + k * 256 + t;
        const int seg = (cidx[e] << 2) | sidx[e];
        const int bkt = seg >> 5;
        const int r = atomicAdd(&lcnt[bkt], 1);
        records[bb[bkt] + r] = ((unsigned)(seg & 31) << 20) | (unsigned)e;
    }
}

// ---------- 5: compute — 512 thr; 16 lanes/segment (2 halves); xor-reduce flush ----------
__global__ __launch_bounds__(512) void compute_kernel(
    const unsigned int* __restrict__ records,
    const int* __restrict__ offsets, const int* __restrict__ counts,
    const float* __restrict__ vectors,
    const float* __restrict__ rw,    // (4,12,8)
    float* __restrict__ out)
{
    __shared__ float4 pay[PAY_SZ];             // 39.2 KB: per edge ph[12]+sh[16], j-padded
    __shared__ int shist[SEG_PER_BKT];
    __shared__ int soff[SEG_PER_BKT + 1];
    __shared__ int scur[SEG_PER_BKT];

    const int t = threadIdx.x;
    const int b = blockIdx.x;                  // 4096 buckets
    const int n = t & 7;                       // radial index owned by this lane
    const int h = (t >> 3) & 1;                // half within group
    const int g = t >> 4;                      // group 0..31; owns segment g

    const int off = offsets[b];
    const int cnt = counts[b];

    // per-lane W slice
    float Wn[4][N_BASIS];
    #pragma unroll
    for (int l = 0; l < 4; ++l)
        #pragma unroll
        for (int bb2 = 0; bb2 < N_BASIS; ++bb2)
            Wn[l][bb2] = rw[(l * N_BASIS + bb2) * 8 + n];

    if (cnt > CAP) {
        // correctness-only slow path (P ~ 8e-5 per run); half 0 does the work
        if (h == 0) {
            float acc[16];
            #pragma unroll
            for (int L = 0; L < 16; ++L) acc[L] = 0.0f;
            for (int j = 0; j < cnt; ++j) {
                const unsigned rec = records[off + j];
                if ((int)(rec >> 20) != g) continue;
                const int eid = rec & 0xFFFFF;
                float ph[N_BASIS], sh[16];
                compute_edge(vectors[3*eid], vectors[3*eid+1], vectors[3*eid+2], ph, sh);
                float rad[4];
                #pragma unroll
                for (int l = 0; l < 4; ++l) {
                    float a = 0.0f;
                    #pragma unroll
                    for (int bb2 = 0; bb2 < N_BASIS; ++bb2)
                        a = fmaf(ph[bb2], Wn[l][bb2], a);
                    rad[l] = a;
                }
                #pragma unroll
                for (int L = 0; L < 16; ++L) {
                    const int l = (L == 0) ? 0 : (L < 4) ? 1 : (L < 9) ? 2 : 3;
                    acc[L] = fmaf(sh[L], rad[l], acc[L]);
                }
            }
            const int seg = b * SEG_PER_BKT + g;
            float* op = out + (size_t)(seg >> 2) * 512 + (seg & 3) * 8 + n;
            #pragma unroll
            for (int L = 0; L < 16; ++L) op[L * 32] = acc[L];
        }
        return;
    }

    if (t < SEG_PER_BKT) shist[t] = 0;
    __syncthreads();

    // pass 1: load records (coalesced 4B, single pass: cnt <= 344 < 512)
    unsigned rec0 = 0;
    if (t < cnt) {
        rec0 = records[off + t];
        atomicAdd(&shist[rec0 >> 20], 1);
    }
    __syncthreads();

    // barrier-free scan of 32 entries on wave 0
    if (t < SEG_PER_BKT) {
        const int hh = shist[t];
        int v = hh;
        #pragma unroll
        for (int d = 1; d < 32; d <<= 1) {
            const int u = __shfl_up(v, d, 32);
            if (t >= d) v += u;
        }
        soff[t] = v - hh;
        scur[t] = v - hh;
        if (t == 31) soff[32] = v;             // sentinel = cnt
    }
    __syncthreads();

    // pass 2: gather xyz + compute_edge ONCE; store ph+sh to swizzled sorted slot
    if (t < cnt) {
        const int sl  = rec0 >> 20;
        const int eid = rec0 & 0xFFFFF;
        const float x = vectors[3 * eid + 0];
        const float y = vectors[3 * eid + 1];
        const float z = vectors[3 * eid + 2];
        const int r = atomicAdd(&scur[sl], 1);
        float ph[N_BASIS], sh[16];
        compute_edge(x, y, z, ph, sh);
        float4* pp = &pay[pslot(r)];
        pp[0] = make_float4(ph[0], ph[1], ph[2], ph[3]);
        pp[1] = make_float4(ph[4], ph[5], ph[6], ph[7]);
        pp[2] = make_float4(ph[8], ph[9], ph[10], ph[11]);
        pp[3] = make_float4(sh[0], sh[1], sh[2], sh[3]);
        pp[4] = make_float4(sh[4], sh[5], sh[6], sh[7]);
        pp[5] = make_float4(sh[8], sh[9], sh[10], sh[11]);
        pp[6] = make_float4(sh[12], sh[13], sh[14], sh[15]);
    }
    __syncthreads();

    // thin walk: 16 lanes per segment; half h takes j = js+h, js+h+2, ...
    const int js = soff[g];
    const int je = soff[g + 1];

    float acc[16];
    #pragma unroll
    for (int L = 0; L < 16; ++L) acc[L] = 0.0f;

    for (int j = js + h; j < je; j += 2) {
        const float4* pp = &pay[pslot(j)];
        const float4 p0 = pp[0], p1 = pp[1], p2 = pp[2];
        const float4 s0 = pp[3], s1 = pp[4], s2 = pp[5], s3 = pp[6];

        float rad[4];
        #pragma unroll
        for (int l = 0; l < 4; ++l) {
            float a =      p0.x * Wn[l][0];
            a = fmaf(p0.y, Wn[l][1],  a);
            a = fmaf(p0.z, Wn[l][2],  a);
            a = fmaf(p0.w, Wn[l][3],  a);
            a = fmaf(p1.x, Wn[l][4],  a);
            a = fmaf(p1.y, Wn[l][5],  a);
            a = fmaf(p1.z, Wn[l][6],  a);
            a = fmaf(p1.w, Wn[l][7],  a);
            a = fmaf(p2.x, Wn[l][8],  a);
            a = fmaf(p2.y, Wn[l][9],  a);
            a = fmaf(p2.z, Wn[l][10], a);
            a = fmaf(p2.w, Wn[l][11], a);
            rad[l] = a;
        }
        acc[0]  = fmaf(s0.x, rad[0], acc[0]);
        acc[1]  = fmaf(s0.y, rad[1], acc[1]);
        acc[2]  = fmaf(s0.z, rad[1], acc[2]);
        acc[3]  = fmaf(s0.w, rad[1], acc[3]);
        acc[4]  = fmaf(s1.x, rad[2], acc[4]);
        acc[5]  = fmaf(s1.y, rad[2], acc[5]);
        acc[6]  = fmaf(s1.z, rad[2], acc[6]);
        acc[7]  = fmaf(s1.w, rad[2], acc[7]);
        acc[8]  = fmaf(s2.x, rad[2], acc[8]);
        acc[9]  = fmaf(s2.y, rad[3], acc[9]);
        acc[10] = fmaf(s2.z, rad[3], acc[10]);
        acc[11] = fmaf(s2.w, rad[3], acc[11]);
        acc[12] = fmaf(s3.x, rad[3], acc[12]);
        acc[13] = fmaf(s3.y, rad[3], acc[13]);
        acc[14] = fmaf(s3.z, rad[3], acc[14]);
        acc[15] = fmaf(s3.w, rad[3], acc[15]);
    }

    // merge halves (xor 8 within the 16-lane group); both end with the sum
    #pragma unroll
    for (int L = 0; L < 16; ++L)
        acc[L] += __shfl_xor(acc[L], 8, 64);

    // split flush: half 0 stores L0-7, half 1 stores L8-15 (covers empty segs too)
    const int seg = b * SEG_PER_BKT + g;
    float* op = out + (size_t)(seg >> 2) * 512 + (seg & 3) * 8 + n;
    const int L0 = h * 8;
    #pragma unroll
    for (int k = 0; k < 8; ++k)
        op[(L0 + k) * 32] = acc[L0 + k];
}

// ---------- fallback: atomic kernel (used only if ws too small) ----------
__global__ __launch_bounds__(256) void atomic_kernel(
    const float* __restrict__ vectors, const float* __restrict__ rw,
    const int* __restrict__ cidx, const int* __restrict__ sidx,
    float* __restrict__ out)
{
    const int e = blockIdx.x * 256 + threadIdx.x;
    if (e >= N_EDGES) return;
    float ph[N_BASIS], sh[16];
    compute_edge(vectors[3*e], vectors[3*e+1], vectors[3*e+2], ph, sh);
    float* op = out + (size_t)cidx[e] * 512 + sidx[e] * 8;
    for (int l = 0; l < 4; ++l) {
        const int L0 = l * l;
        const int ml = 2 * l + 1;
        for (int nn = 0; nn < 8; ++nn) {
            float rad = 0.0f;
            for (int bb2 = 0; bb2 < N_BASIS; ++bb2)
                rad = fmaf(ph[bb2], rw[(l * N_BASIS + bb2) * 8 + nn], rad);
            for (int mm = 0; mm < ml; ++mm)
                atomicAdd(op + (L0 + mm) * 32 + nn, sh[L0 + mm] * rad);
        }
    }
}

extern "C" void kernel_launch(void* const* d_in, const int* in_sizes, int n_in,
                              void* d_out, int out_size, void* d_ws, size_t ws_size,
                              hipStream_t stream) {
    const float* vectors = (const float*)d_in[0];
    const float* rw      = (const float*)d_in[1];
    const int*   cidx    = (const int*)d_in[2];
    const int*   sidx    = (const int*)d_in[3];
    float*       out     = (float*)d_out;

    if (ws_size < (size_t)WS_NEED) {
        hipMemsetAsync(out, 0, (size_t)out_size * sizeof(float), stream);
        hipLaunchKernelGGL(atomic_kernel, dim3(N_EDGES / 256), dim3(256), 0, stream,
                           vectors, rw, cidx, sidx, out);
        return;
    }

    char* ws = (char*)d_ws;
    int*          blkhist = (int*)(ws + WS_BLKHIST);
    int*          totals  = (int*)(ws + WS_TOTALS);
    int*          offsets = (int*)(ws + WS_OFFSETS);
    unsigned int* records = (unsigned int*)(ws + WS_REC);

    hipLaunchKernelGGL(hist_kernel,      dim3(HBLK),     dim3(256),  0, stream, cidx, sidx, blkhist);
    hipLaunchKernelGGL(scanA_kernel,     dim3(NBKT/128), dim3(128),  0, stream, blkhist, totals);
    hipLaunchKernelGGL(scanB_kernel,     dim3(1),        dim3(1024), 0, stream, totals, offsets);
    hipLaunchKernelGGL(partition_kernel, dim3(HBLK),     dim3(256),  0, stream, cidx, sidx, blkhist, offsets, records);
    hipLaunchKernelGGL(compute_kernel,   dim3(NBKT),     dim3(512),  0, stream, records, offsets, totals, vectors, rw, out);
}

// Round 18
// 150.987 us; speedup vs baseline: 1.2849x; 1.2849x over previous
//
#include <hip/hip_runtime.h>
#include <math.h>

#define N_EDGES     1048576
#define NBKT        4096         // bucket = seg >> 5 (32 segs / bucket)
#define SEG_PER_BKT 32
#define N_BASIS     12
#define CAP         344          // per-bucket capacity (Poisson(256)+5.5sd; slow path kept)
#define PAY_SZ      (CAP * 7 + CAP / 8)   // j-padded: slot(j) = 7j + (j>>3)
#define HBLK        256          // hist/partition blocks (256 threads each)
#define HEPB        (N_EDGES / HBLK)   // 4096 edges per block

// rec = (sl << 20) | eid   (sl = seg & 31, eid < 2^20)

// ---- workspace layout (8.03 MB) ----
#define WS_BLKHIST  0                          // int[HBLK][NBKT]  (4 MB)
#define WS_TOTALS   (HBLK * NBKT * 4)          // int[NBKT] (16 KB)
#define WS_OFFSETS  (WS_TOTALS + NBKT * 4)     // int[NBKT] (16 KB)
#define WS_REC      (WS_OFFSETS + NBKT * 4)    // u32[N_EDGES] (4 MB)
#define WS_NEED     (WS_REC + (size_t)N_EDGES * 4)

__device__ __forceinline__ int pslot(int j) { return j * 7 + (j >> 3); }

__device__ __forceinline__ void compute_edge(float x, float y, float z,
                                             float* __restrict__ ph,   // 12, scaled by NORM/r
                                             float* __restrict__ sh)   // 16
{
    const float r2    = fmaf(x, x, fmaf(y, y, z * z)) + 1e-12f;
    const float inv_r = rsqrtf(r2);
    const float r     = r2 * inv_r;
    x *= inv_r; y *= inv_r; z *= inv_r;

    const float t = 0.6283185307179586f * r;   // pi/5 * r
    float s1, c1;
    __sincosf(t, &s1, &c1);
    const float twoc = 2.0f * c1;
    const float scale = 0.17677669529663687f * inv_r;  // (1/sqrt(32)) / r
    float skm1 = 0.0f, sk = s1;
    #pragma unroll
    for (int b = 0; b < N_BASIS; ++b) {
        ph[b] = sk * scale;
        const float nxt = fmaf(twoc, sk, -skm1);
        skm1 = sk; sk = nxt;
    }

    const float x2 = x * x, y2 = y * y, z2 = z * z;
    sh[0]  = 0.28209479177387814f;
    sh[1]  = 0.4886025119029199f * y;
    sh[2]  = 0.4886025119029199f * z;
    sh[3]  = 0.4886025119029199f * x;
    sh[4]  = 1.0925484305920792f * x * y;
    sh[5]  = 1.0925484305920792f * y * z;
    sh[6]  = 0.31539156525252005f * (3.0f * z2 - 1.0f);
    sh[7]  = 1.0925484305920792f * x * z;
    sh[8]  = 0.5462742152960396f * (x2 - y2);
    sh[9]  = 0.5900435899266435f * y * (3.0f * x2 - y2);
    sh[10] = 2.890611442640554f  * x * y * z;
    sh[11] = 0.4570457994644658f * y * (5.0f * z2 - 1.0f);
    sh[12] = 0.3731763325901154f * (5.0f * z2 * z - 3.0f * z);
    sh[13] = 0.4570457994644658f * x * (5.0f * z2 - 1.0f);
    sh[14] = 1.445305721320277f  * z * (x2 - y2);
    sh[15] = 0.5900435899266435f * x * (x2 - y2);
}

// ---------- 1: per-block histogram (LDS only; coalesced writeout) ----------
__global__ __launch_bounds__(256) void hist_kernel(
    const int* __restrict__ cidx, const int* __restrict__ sidx,
    int* __restrict__ blkhist)
{
    __shared__ int h[NBKT];                    // 16 KB
    const int t = threadIdx.x;
    #pragma unroll
    for (int i = t; i < NBKT; i += 256) h[i] = 0;
    __syncthreads();
    const int base = blockIdx.x * HEPB;
    #pragma unroll
    for (int k = 0; k < HEPB / 256; ++k) {
        const int e = base + k * 256 + t;
        const int seg = (cidx[e] << 2) | sidx[e];
        atomicAdd(&h[seg >> 5], 1);
    }
    __syncthreads();
    #pragma unroll
    for (int i = t; i < NBKT; i += 256)
        blkhist[blockIdx.x * NBKT + i] = h[i];
}

// ---------- 2: per-bucket exclusive scan over the 256 hist rows (in-place) ----------
__global__ __launch_bounds__(128) void scanA_kernel(
    int* __restrict__ blkhist, int* __restrict__ totals)
{
    const int bkt = blockIdx.x * 128 + threadIdx.x;   // 4096 threads, 32 blocks
    int run = 0;
    for (int blk = 0; blk < HBLK; ++blk) {
        const int v = blkhist[blk * NBKT + bkt];      // coalesced per row
        blkhist[blk * NBKT + bkt] = run;              // exclusive within bucket
        run += v;
    }
    totals[bkt] = run;
}

// ---------- 3: partition with fused offsets-scan (scanB absorbed) ----------
__global__ __launch_bounds__(256) void partition_kernel(
    const int* __restrict__ cidx, const int* __restrict__ sidx,
    const int* __restrict__ blkhist, const int* __restrict__ totals,
    unsigned int* __restrict__ records, int* __restrict__ offsets_g)
{
    __shared__ int off_s[NBKT];                // 16 KB: offsets, then bases in-place
    __shared__ int lcnt[NBKT];                 // 16 KB
    __shared__ int tmp[256];
    const int t  = threadIdx.x;
    const int me = blockIdx.x;

    // redundant exclusive scan of the 4096 totals (serial-16 + 256-ladder)
    int loc[16];
    int s = 0;
    const int base16 = t * 16;
    #pragma unroll
    for (int k = 0; k < 16; ++k) { loc[k] = s; s += totals[base16 + k]; }
    tmp[t] = s;
    __syncthreads();
    #pragma unroll
    for (int d = 1; d < 256; d <<= 1) {
        const int v = (t >= d) ? tmp[t - d] : 0;
        __syncthreads();
        tmp[t] += v;
        __syncthreads();
    }
    const int ex = tmp[t] - s;
    #pragma unroll
    for (int k = 0; k < 16; ++k) off_s[base16 + k] = ex + loc[k];
    __syncthreads();

    // block 0 publishes offsets for the compute kernel
    if (me == 0) {
        #pragma unroll
        for (int k = 0; k < 16; ++k) offsets_g[base16 + k] = off_s[base16 + k];
    }

    // in-place bases for this block + zero rank counters
    #pragma unroll
    for (int i = t; i < NBKT; i += 256) {
        off_s[i] += blkhist[me * NBKT + i];
        lcnt[i] = 0;
    }
    __syncthreads();

    const int base = me * HEPB;
    #pragma unroll
    for (int k = 0; k < HEPB / 256; ++k) {
        const int e = base + k * 256 + t;
        const int seg = (cidx[e] << 2) | sidx[e];
        const int bkt = seg >> 5;
        const int r = atomicAdd(&lcnt[bkt], 1);
        records[off_s[bkt] + r] = ((unsigned)(seg & 31) << 20) | (unsigned)e;
    }
}

// ---------- 4: compute — ph+sh shared via swizzled LDS; thin walk (R16 body) ----------
__global__ __launch_bounds__(256) void compute_kernel(
    const unsigned int* __restrict__ records,
    const int* __restrict__ offsets, const int* __restrict__ counts,
    const float* __restrict__ vectors,
    const float* __restrict__ rw,    // (4,12,8)
    float* __restrict__ out)
{
    __shared__ float4 pay[PAY_SZ];             // 39.2 KB: per edge ph[12]+sh[16], j-padded
    __shared__ int shist[SEG_PER_BKT];
    __shared__ int soff[SEG_PER_BKT + 1];
    __shared__ int scur[SEG_PER_BKT];

    const int t = threadIdx.x;
    const int b = blockIdx.x;                  // 4096 buckets
    const int n = t & 7;                       // radial index owned by this lane
    const int g = t >> 3;                      // group 0..31; owns segment g

    const int off = offsets[b];
    const int cnt = counts[b];

    if (cnt > CAP) {
        // correctness-only slow path (P ~ 8e-5 per run)
        float Wn[4][N_BASIS];
        #pragma unroll
        for (int l = 0; l < 4; ++l)
            #pragma unroll
            for (int bb2 = 0; bb2 < N_BASIS; ++bb2)
                Wn[l][bb2] = rw[(l * N_BASIS + bb2) * 8 + n];
        float acc[16];
        #pragma unroll
        for (int L = 0; L < 16; ++L) acc[L] = 0.0f;
        for (int j = 0; j < cnt; ++j) {
            const unsigned rec = records[off + j];
            if ((int)(rec >> 20) != g) continue;
            const int eid = rec & 0xFFFFF;
            float ph[N_BASIS], sh[16];
            compute_edge(vectors[3*eid], vectors[3*eid+1], vectors[3*eid+2], ph, sh);
            float rad[4];
            #pragma unroll
            for (int l = 0; l < 4; ++l) {
                float a = 0.0f;
                #pragma unroll
                for (int bb2 = 0; bb2 < N_BASIS; ++bb2)
                    a = fmaf(ph[bb2], Wn[l][bb2], a);
                rad[l] = a;
            }
            #pragma unroll
            for (int L = 0; L < 16; ++L) {
                const int l = (L == 0) ? 0 : (L < 4) ? 1 : (L < 9) ? 2 : 3;
                acc[L] = fmaf(sh[L], rad[l], acc[L]);
            }
        }
        const int seg = b * SEG_PER_BKT + g;
        float* op = out + (size_t)(seg >> 2) * 512 + (seg & 3) * 8 + n;
        #pragma unroll
        for (int L = 0; L < 16; ++L) op[L * 32] = acc[L];
        return;
    }

    if (t < SEG_PER_BKT) shist[t] = 0;
    __syncthreads();

    // pass 1: load records (coalesced 4B), histogram by local segment
    unsigned recs[2];
    const int iters = (cnt + 255) >> 8;        // <= 2
    #pragma unroll
    for (int it = 0; it < 2; ++it) {
        const int i = it * 256 + t;
        if (it < iters && i < cnt) {
            recs[it] = records[off + i];
            atomicAdd(&shist[recs[it] >> 20], 1);
        }
    }
    __syncthreads();

    // barrier-free scan of 32 entries on wave 0
    if (t < SEG_PER_BKT) {
        const int h = shist[t];
        int v = h;
        #pragma unroll
        for (int d = 1; d < 32; d <<= 1) {
            const int u = __shfl_up(v, d, 32);
            if (t >= d) v += u;
        }
        soff[t] = v - h;
        scur[t] = v - h;
        if (t == 31) soff[32] = v;             // sentinel = cnt
    }
    __syncthreads();

    // pass 2: gather xyz (parallel) + compute_edge ONCE; store ph+sh to swizzled slot
    #pragma unroll
    for (int it = 0; it < 2; ++it) {
        const int i = it * 256 + t;
        if (it < iters && i < cnt) {
            const int sl  = recs[it] >> 20;
            const int eid = recs[it] & 0xFFFFF;
            const float x = vectors[3 * eid + 0];
            const float y = vectors[3 * eid + 1];
            const float z = vectors[3 * eid + 2];
            const int r = atomicAdd(&scur[sl], 1);
            float ph[N_BASIS], sh[16];
            compute_edge(x, y, z, ph, sh);
            float4* pp = &pay[pslot(r)];
            pp[0] = make_float4(ph[0], ph[1], ph[2], ph[3]);
            pp[1] = make_float4(ph[4], ph[5], ph[6], ph[7]);
            pp[2] = make_float4(ph[8], ph[9], ph[10], ph[11]);
            pp[3] = make_float4(sh[0], sh[1], sh[2], sh[3]);
            pp[4] = make_float4(sh[4], sh[5], sh[6], sh[7]);
            pp[5] = make_float4(sh[8], sh[9], sh[10], sh[11]);
            pp[6] = make_float4(sh[12], sh[13], sh[14], sh[15]);
        }
    }
    __syncthreads();

    // per-lane W slice
    float Wn[4][N_BASIS];
    #pragma unroll
    for (int l = 0; l < 4; ++l)
        #pragma unroll
        for (int bb2 = 0; bb2 < N_BASIS; ++bb2)
            Wn[l][bb2] = rw[(l * N_BASIS + bb2) * 8 + n];

    // thin walk: group g owns segment g; broadcast b128 reads; rad+acc only
    const int js = soff[g];
    const int je = soff[g + 1];

    float acc[16];
    #pragma unroll
    for (int L = 0; L < 16; ++L) acc[L] = 0.0f;

    for (int j = js; j < je; ++j) {
        const float4* pp = &pay[pslot(j)];
        const float4 p0 = pp[0], p1 = pp[1], p2 = pp[2];
        const float4 s0 = pp[3], s1 = pp[4], s2 = pp[5], s3 = pp[6];

        float rad[4];
        #pragma unroll
        for (int l = 0; l < 4; ++l) {
            float a =      p0.x * Wn[l][0];
            a = fmaf(p0.y, Wn[l][1],  a);
            a = fmaf(p0.z, Wn[l][2],  a);
            a = fmaf(p0.w, Wn[l][3],  a);
            a = fmaf(p1.x, Wn[l][4],  a);
            a = fmaf(p1.y, Wn[l][5],  a);
            a = fmaf(p1.z, Wn[l][6],  a);
            a = fmaf(p1.w, Wn[l][7],  a);
            a = fmaf(p2.x, Wn[l][8],  a);
            a = fmaf(p2.y, Wn[l][9],  a);
            a = fmaf(p2.z, Wn[l][10], a);
            a = fmaf(p2.w, Wn[l][11], a);
            rad[l] = a;
        }
        acc[0]  = fmaf(s0.x, rad[0], acc[0]);
        acc[1]  = fmaf(s0.y, rad[1], acc[1]);
        acc[2]  = fmaf(s0.z, rad[1], acc[2]);
        acc[3]  = fmaf(s0.w, rad[1], acc[3]);
        acc[4]  = fmaf(s1.x, rad[2], acc[4]);
        acc[5]  = fmaf(s1.y, rad[2], acc[5]);
        acc[6]  = fmaf(s1.z, rad[2], acc[6]);
        acc[7]  = fmaf(s1.w, rad[2], acc[7]);
        acc[8]  = fmaf(s2.x, rad[2], acc[8]);
        acc[9]  = fmaf(s2.y, rad[3], acc[9]);
        acc[10] = fmaf(s2.z, rad[3], acc[10]);
        acc[11] = fmaf(s2.w, rad[3], acc[11]);
        acc[12] = fmaf(s3.x, rad[3], acc[12]);
        acc[13] = fmaf(s3.y, rad[3], acc[13]);
        acc[14] = fmaf(s3.z, rad[3], acc[14]);
        acc[15] = fmaf(s3.w, rad[3], acc[15]);
    }

    // unconditional flush (covers empty segments: acc stays zero)
    const int seg = b * SEG_PER_BKT + g;
    float* op = out + (size_t)(seg >> 2) * 512 + (seg & 3) * 8 + n;
    #pragma unroll
    for (int L = 0; L < 16; ++L) op[L * 32] = acc[L];
}

// ---------- fallback: atomic kernel (used only if ws too small) ----------
__global__ __launch_bounds__(256) void atomic_kernel(
    const float* __restrict__ vectors, const float* __restrict__ rw,
    const int* __restrict__ cidx, const int* __restrict__ sidx,
    float* __restrict__ out)
{
    const int e = blockIdx.x * 256 + threadIdx.x;
    if (e >= N_EDGES) return;
    float ph[N_BASIS], sh[16];
    compute_edge(vectors[3*e], vectors[3*e+1], vectors[3*e+2], ph, sh);
    float* op = out + (size_t)cidx[e] * 512 + sidx[e] * 8;
    for (int l = 0; l < 4; ++l) {
        const int L0 = l * l;
        const int ml = 2 * l + 1;
        for (int nn = 0; nn < 8; ++nn) {
            float rad = 0.0f;
            for (int bb2 = 0; bb2 < N_BASIS; ++bb2)
                rad = fmaf(ph[bb2], rw[(l * N_BASIS + bb2) * 8 + nn], rad);
            for (int mm = 0; mm < ml; ++mm)
                atomicAdd(op + (L0 + mm) * 32 + nn, sh[L0 + mm] * rad);
        }
    }
}

extern "C" void kernel_launch(void* const* d_in, const int* in_sizes, int n_in,
                              void* d_out, int out_size, void* d_ws, size_t ws_size,
                              hipStream_t stream) {
    const float* vectors = (const float*)d_in[0];
    const float* rw      = (const float*)d_in[1];
    const int*   cidx    = (const int*)d_in[2];
    const int*   sidx    = (const int*)d_in[3];
    float*       out     = (float*)d_out;

    if (ws_size < (size_t)WS_NEED) {
        hipMemsetAsync(out, 0, (size_t)out_size * sizeof(float), stream);
        hipLaunchKernelGGL(atomic_kernel, dim3(N_EDGES / 256), dim3(256), 0, stream,
                           vectors, rw, cidx, sidx, out);
        return;
    }

    char* ws = (char*)d_ws;
    int*          blkhist = (int*)(ws + WS_BLKHIST);
    int*          totals  = (int*)(ws + WS_TOTALS);
    int*          offsets = (int*)(ws + WS_OFFSETS);
    unsigned int* records = (unsigned int*)(ws + WS_REC);

    hipLaunchKernelGGL(hist_kernel,      dim3(HBLK),     dim3(256), 0, stream, cidx, sidx, blkhist);
    hipLaunchKernelGGL(scanA_kernel,     dim3(NBKT/128), dim3(128), 0, stream, blkhist, totals);
    hipLaunchKernelGGL(partition_kernel, dim3(HBLK),     dim3(256), 0, stream, cidx, sidx, blkhist, totals, records, offsets);
    hipLaunchKernelGGL(compute_kernel,   dim3(NBKT),     dim3(256), 0, stream, records, offsets, totals, vectors, rw, out);
}

// Round 19
// 146.837 us; speedup vs baseline: 1.3212x; 1.0283x over previous
//
#include <hip/hip_runtime.h>
#include <math.h>

#define N_EDGES     1048576
#define NBKT        4096         // bucket = seg >> 5 (32 segs / bucket)
#define SEG_PER_BKT 32
#define N_BASIS     12
#define CAP         344          // per-bucket capacity (Poisson(256)+5.5sd; slow path kept)
#define PAY_SZ      (CAP * 7 + CAP / 8)   // j-padded: slot(j) = 7j + (j>>3)
#define HBLK        256          // hist/partition blocks (256 threads each)
#define HEPB        (N_EDGES / HBLK)   // 4096 edges per block

// rec = (sl << 20) | eid   (sl = seg & 31, eid < 2^20)

// ---- workspace layout (8.03 MB) ----
#define WS_BLKHIST  0                          // int[HBLK][NBKT]  (4 MB)
#define WS_TOTALS   (HBLK * NBKT * 4)          // int[NBKT] (16 KB)
#define WS_OFFSETS  (WS_TOTALS + NBKT * 4)     // int[NBKT] (16 KB)
#define WS_REC      (WS_OFFSETS + NBKT * 4)    // u32[N_EDGES] (4 MB)
#define WS_NEED     (WS_REC + (size_t)N_EDGES * 4)

__device__ __forceinline__ int pslot(int j) { return j * 7 + (j >> 3); }

__device__ __forceinline__ void compute_edge(float x, float y, float z,
                                             float* __restrict__ ph,   // 12, scaled by NORM/r
                                             float* __restrict__ sh)   // 16
{
    const float r2    = fmaf(x, x, fmaf(y, y, z * z)) + 1e-12f;
    const float inv_r = rsqrtf(r2);
    const float r     = r2 * inv_r;
    x *= inv_r; y *= inv_r; z *= inv_r;

    const float t = 0.6283185307179586f * r;   // pi/5 * r
    float s1, c1;
    __sincosf(t, &s1, &c1);
    const float twoc = 2.0f * c1;
    const float scale = 0.17677669529663687f * inv_r;  // (1/sqrt(32)) / r
    float skm1 = 0.0f, sk = s1;
    #pragma unroll
    for (int b = 0; b < N_BASIS; ++b) {
        ph[b] = sk * scale;
        const float nxt = fmaf(twoc, sk, -skm1);
        skm1 = sk; sk = nxt;
    }

    const float x2 = x * x, y2 = y * y, z2 = z * z;
    sh[0]  = 0.28209479177387814f;
    sh[1]  = 0.4886025119029199f * y;
    sh[2]  = 0.4886025119029199f * z;
    sh[3]  = 0.4886025119029199f * x;
    sh[4]  = 1.0925484305920792f * x * y;
    sh[5]  = 1.0925484305920792f * y * z;
    sh[6]  = 0.31539156525252005f * (3.0f * z2 - 1.0f);
    sh[7]  = 1.0925484305920792f * x * z;
    sh[8]  = 0.5462742152960396f * (x2 - y2);
    sh[9]  = 0.5900435899266435f * y * (3.0f * x2 - y2);
    sh[10] = 2.890611442640554f  * x * y * z;
    sh[11] = 0.4570457994644658f * y * (5.0f * z2 - 1.0f);
    sh[12] = 0.3731763325901154f * (5.0f * z2 * z - 3.0f * z);
    sh[13] = 0.4570457994644658f * x * (5.0f * z2 - 1.0f);
    sh[14] = 1.445305721320277f  * z * (x2 - y2);
    sh[15] = 0.5900435899266435f * x * (x2 - y2);
}

// ---------- 1: per-block histogram (int4 index loads; LDS only) ----------
__global__ __launch_bounds__(256) void hist_kernel(
    const int* __restrict__ cidx, const int* __restrict__ sidx,
    int* __restrict__ blkhist)
{
    __shared__ int h[NBKT];                    // 16 KB
    const int t = threadIdx.x;
    #pragma unroll
    for (int i = t; i < NBKT; i += 256) h[i] = 0;
    __syncthreads();
    const int base4 = blockIdx.x * (HEPB / 4);
    #pragma unroll
    for (int k = 0; k < HEPB / 1024; ++k) {    // 4 iterations of int4
        const int e4 = base4 + k * 256 + t;
        const int4 c = ((const int4*)cidx)[e4];
        const int4 s = ((const int4*)sidx)[e4];
        atomicAdd(&h[((c.x << 2) | s.x) >> 5], 1);
        atomicAdd(&h[((c.y << 2) | s.y) >> 5], 1);
        atomicAdd(&h[((c.z << 2) | s.z) >> 5], 1);
        atomicAdd(&h[((c.w << 2) | s.w) >> 5], 1);
    }
    __syncthreads();
    #pragma unroll
    for (int i = t; i < NBKT; i += 256)
        blkhist[blockIdx.x * NBKT + i] = h[i];
}

// ---------- 2: per-bucket exclusive scan; 8-wide batched loads (latency fix) ----------
__global__ __launch_bounds__(128) void scanA_kernel(
    int* __restrict__ blkhist, int* __restrict__ totals)
{
    const int bkt = blockIdx.x * 128 + threadIdx.x;   // 4096 threads, 32 blocks
    int run = 0;
    for (int blk0 = 0; blk0 < HBLK; blk0 += 8) {
        int v[8];
        #pragma unroll
        for (int u = 0; u < 8; ++u)
            v[u] = blkhist[(blk0 + u) * NBKT + bkt];  // 8 loads in flight
        #pragma unroll
        for (int u = 0; u < 8; ++u) {
            blkhist[(blk0 + u) * NBKT + bkt] = run;   // exclusive within bucket
            run += v[u];
        }
    }
    totals[bkt] = run;
}

// ---------- 3: partition with fused offsets-scan (int4 index loads) ----------
__global__ __launch_bounds__(256) void partition_kernel(
    const int* __restrict__ cidx, const int* __restrict__ sidx,
    const int* __restrict__ blkhist, const int* __restrict__ totals,
    unsigned int* __restrict__ records, int* __restrict__ offsets_g)
{
    __shared__ int off_s[NBKT];                // 16 KB: offsets, then bases in-place
    __shared__ int lcnt[NBKT];                 // 16 KB
    __shared__ int tmp[256];
    const int t  = threadIdx.x;
    const int me = blockIdx.x;

    // redundant exclusive scan of the 4096 totals (serial-16 + 256-ladder)
    int loc[16];
    int s = 0;
    const int base16 = t * 16;
    #pragma unroll
    for (int k = 0; k < 16; ++k) { loc[k] = s; s += totals[base16 + k]; }
    tmp[t] = s;
    __syncthreads();
    #pragma unroll
    for (int d = 1; d < 256; d <<= 1) {
        const int v = (t >= d) ? tmp[t - d] : 0;
        __syncthreads();
        tmp[t] += v;
        __syncthreads();
    }
    const int ex = tmp[t] - s;
    #pragma unroll
    for (int k = 0; k < 16; ++k) off_s[base16 + k] = ex + loc[k];
    __syncthreads();

    // block 0 publishes offsets for the compute kernel
    if (me == 0) {
        #pragma unroll
        for (int k = 0; k < 16; ++k) offsets_g[base16 + k] = off_s[base16 + k];
    }

    // in-place bases for this block + zero rank counters
    #pragma unroll
    for (int i = t; i < NBKT; i += 256) {
        off_s[i] += blkhist[me * NBKT + i];
        lcnt[i] = 0;
    }
    __syncthreads();

    const int base  = me * HEPB;
    const int base4 = me * (HEPB / 4);
    #pragma unroll
    for (int k = 0; k < HEPB / 1024; ++k) {    // 4 iterations of int4
        const int e4 = base4 + k * 256 + t;
        const int4 c = ((const int4*)cidx)[e4];
        const int4 s4 = ((const int4*)sidx)[e4];
        const int e0 = base + (k * 256 + t) * 4;
        int segs[4];
        segs[0] = (c.x << 2) | s4.x;
        segs[1] = (c.y << 2) | s4.y;
        segs[2] = (c.z << 2) | s4.z;
        segs[3] = (c.w << 2) | s4.w;
        #pragma unroll
        for (int j = 0; j < 4; ++j) {
            const int seg = segs[j];
            const int bkt = seg >> 5;
            const int r = atomicAdd(&lcnt[bkt], 1);
            records[off_s[bkt] + r] = ((unsigned)(seg & 31) << 20) | (unsigned)(e0 + j);
        }
    }
}

// ---------- 4: compute — ph+sh shared via swizzled LDS; thin walk (R18 body, frozen) ----------
__global__ __launch_bounds__(256) void compute_kernel(
    const unsigned int* __restrict__ records,
    const int* __restrict__ offsets, const int* __restrict__ counts,
    const float* __restrict__ vectors,
    const float* __restrict__ rw,    // (4,12,8)
    float* __restrict__ out)
{
    __shared__ float4 pay[PAY_SZ];             // 39.2 KB: per edge ph[12]+sh[16], j-padded
    __shared__ int shist[SEG_PER_BKT];
    __shared__ int soff[SEG_PER_BKT + 1];
    __shared__ int scur[SEG_PER_BKT];

    const int t = threadIdx.x;
    const int b = blockIdx.x;                  // 4096 buckets
    const int n = t & 7;                       // radial index owned by this lane
    const int g = t >> 3;                      // group 0..31; owns segment g

    const int off = offsets[b];
    const int cnt = counts[b];

    if (cnt > CAP) {
        // correctness-only slow path (P ~ 8e-5 per run)
        float Wn[4][N_BASIS];
        #pragma unroll
        for (int l = 0; l < 4; ++l)
            #pragma unroll
            for (int bb2 = 0; bb2 < N_BASIS; ++bb2)
                Wn[l][bb2] = rw[(l * N_BASIS + bb2) * 8 + n];
        float acc[16];
        #pragma unroll
        for (int L = 0; L < 16; ++L) acc[L] = 0.0f;
        for (int j = 0; j < cnt; ++j) {
            const unsigned rec = records[off + j];
            if ((int)(rec >> 20) != g) continue;
            const int eid = rec & 0xFFFFF;
            float ph[N_BASIS], sh[16];
            compute_edge(vectors[3*eid], vectors[3*eid+1], vectors[3*eid+2], ph, sh);
            float rad[4];
            #pragma unroll
            for (int l = 0; l < 4; ++l) {
                float a = 0.0f;
                #pragma unroll
                for (int bb2 = 0; bb2 < N_BASIS; ++bb2)
                    a = fmaf(ph[bb2], Wn[l][bb2], a);
                rad[l] = a;
            }
            #pragma unroll
            for (int L = 0; L < 16; ++L) {
                const int l = (L == 0) ? 0 : (L < 4) ? 1 : (L < 9) ? 2 : 3;
                acc[L] = fmaf(sh[L], rad[l], acc[L]);
            }
        }
        const int seg = b * SEG_PER_BKT + g;
        float* op = out + (size_t)(seg >> 2) * 512 + (seg & 3) * 8 + n;
        #pragma unroll
        for (int L = 0; L < 16; ++L) op[L * 32] = acc[L];
        return;
    }

    if (t < SEG_PER_BKT) shist[t] = 0;
    __syncthreads();

    // pass 1: load records (coalesced 4B), histogram by local segment
    unsigned recs[2];
    const int iters = (cnt + 255) >> 8;        // <= 2
    #pragma unroll
    for (int it = 0; it < 2; ++it) {
        const int i = it * 256 + t;
        if (it < iters && i < cnt) {
            recs[it] = records[off + i];
            atomicAdd(&shist[recs[it] >> 20], 1);
        }
    }
    __syncthreads();

    // barrier-free scan of 32 entries on wave 0
    if (t < SEG_PER_BKT) {
        const int h = shist[t];
        int v = h;
        #pragma unroll
        for (int d = 1; d < 32; d <<= 1) {
            const int u = __shfl_up(v, d, 32);
            if (t >= d) v += u;
        }
        soff[t] = v - h;
        scur[t] = v - h;
        if (t == 31) soff[32] = v;             // sentinel = cnt
    }
    __syncthreads();

    // pass 2: gather xyz (parallel) + compute_edge ONCE; store ph+sh to swizzled slot
    #pragma unroll
    for (int it = 0; it < 2; ++it) {
        const int i = it * 256 + t;
        if (it < iters && i < cnt) {
            const int sl  = recs[it] >> 20;
            const int eid = recs[it] & 0xFFFFF;
            const float x = vectors[3 * eid + 0];
            const float y = vectors[3 * eid + 1];
            const float z = vectors[3 * eid + 2];
            const int r = atomicAdd(&scur[sl], 1);
            float ph[N_BASIS], sh[16];
            compute_edge(x, y, z, ph, sh);
            float4* pp = &pay[pslot(r)];
            pp[0] = make_float4(ph[0], ph[1], ph[2], ph[3]);
            pp[1] = make_float4(ph[4], ph[5], ph[6], ph[7]);
            pp[2] = make_float4(ph[8], ph[9], ph[10], ph[11]);
            pp[3] = make_float4(sh[0], sh[1], sh[2], sh[3]);
            pp[4] = make_float4(sh[4], sh[5], sh[6], sh[7]);
            pp[5] = make_float4(sh[8], sh[9], sh[10], sh[11]);
            pp[6] = make_float4(sh[12], sh[13], sh[14], sh[15]);
        }
    }
    __syncthreads();

    // per-lane W slice
    float Wn[4][N_BASIS];
    #pragma unroll
    for (int l = 0; l < 4; ++l)
        #pragma unroll
        for (int bb2 = 0; bb2 < N_BASIS; ++bb2)
            Wn[l][bb2] = rw[(l * N_BASIS + bb2) * 8 + n];

    // thin walk: group g owns segment g; broadcast b128 reads; rad+acc only
    const int js = soff[g];
    const int je = soff[g + 1];

    float acc[16];
    #pragma unroll
    for (int L = 0; L < 16; ++L) acc[L] = 0.0f;

    for (int j = js; j < je; ++j) {
        const float4* pp = &pay[pslot(j)];
        const float4 p0 = pp[0], p1 = pp[1], p2 = pp[2];
        const float4 s0 = pp[3], s1 = pp[4], s2 = pp[5], s3 = pp[6];

        float rad[4];
        #pragma unroll
        for (int l = 0; l < 4; ++l) {
            float a =      p0.x * Wn[l][0];
            a = fmaf(p0.y, Wn[l][1],  a);
            a = fmaf(p0.z, Wn[l][2],  a);
            a = fmaf(p0.w, Wn[l][3],  a);
            a = fmaf(p1.x, Wn[l][4],  a);
            a = fmaf(p1.y, Wn[l][5],  a);
            a = fmaf(p1.z, Wn[l][6],  a);
            a = fmaf(p1.w, Wn[l][7],  a);
            a = fmaf(p2.x, Wn[l][8],  a);
            a = fmaf(p2.y, Wn[l][9],  a);
            a = fmaf(p2.z, Wn[l][10], a);
            a = fmaf(p2.w, Wn[l][11], a);
            rad[l] = a;
        }
        acc[0]  = fmaf(s0.x, rad[0], acc[0]);
        acc[1]  = fmaf(s0.y, rad[1], acc[1]);
        acc[2]  = fmaf(s0.z, rad[1], acc[2]);
        acc[3]  = fmaf(s0.w, rad[1], acc[3]);
        acc[4]  = fmaf(s1.x, rad[2], acc[4]);
        acc[5]  = fmaf(s1.y, rad[2], acc[5]);
        acc[6]  = fmaf(s1.z, rad[2], acc[6]);
        acc[7]  = fmaf(s1.w, rad[2], acc[7]);
        acc[8]  = fmaf(s2.x, rad[2], acc[8]);
        acc[9]  = fmaf(s2.y, rad[3], acc[9]);
        acc[10] = fmaf(s2.z, rad[3], acc[10]);
        acc[11] = fmaf(s2.w, rad[3], acc[11]);
        acc[12] = fmaf(s3.x, rad[3], acc[12]);
        acc[13] = fmaf(s3.y, rad[3], acc[13]);
        acc[14] = fmaf(s3.z, rad[3], acc[14]);
        acc[15] = fmaf(s3.w, rad[3], acc[15]);
    }

    // unconditional flush (covers empty segments: acc stays zero)
    const int seg = b * SEG_PER_BKT + g;
    float* op = out + (size_t)(seg >> 2) * 512 + (seg & 3) * 8 + n;
    #pragma unroll
    for (int L = 0; L < 16; ++L) op[L * 32] = acc[L];
}

// ---------- fallback: atomic kernel (used only if ws too small) ----------
__global__ __launch_bounds__(256) void atomic_kernel(
    const float* __restrict__ vectors, const float* __restrict__ rw,
    const int* __restrict__ cidx, const int* __restrict__ sidx,
    float* __restrict__ out)
{
    const int e = blockIdx.x * 256 + threadIdx.x;
    if (e >= N_EDGES) return;
    float ph[N_BASIS], sh[16];
    compute_edge(vectors[3*e], vectors[3*e+1], vectors[3*e+2], ph, sh);
    float* op = out + (size_t)cidx[e] * 512 + sidx[e] * 8;
    for (int l = 0; l < 4; ++l) {
        const int L0 = l * l;
        const int ml = 2 * l + 1;
        for (int nn = 0; nn < 8; ++nn) {
            float rad = 0.0f;
            for (int bb2 = 0; bb2 < N_BASIS; ++bb2)
                rad = fmaf(ph[bb2], rw[(l * N_BASIS + bb2) * 8 + nn], rad);
            for (int mm = 0; mm < ml; ++mm)
                atomicAdd(op + (L0 + mm) * 32 + nn, sh[L0 + mm] * rad);
        }
    }
}

extern "C" void kernel_launch(void* const* d_in, const int* in_sizes, int n_in,
                              void* d_out, int out_size, void* d_ws, size_t ws_size,
                              hipStream_t stream) {
    const float* vectors = (const float*)d_in[0];
    const float* rw      = (const float*)d_in[1];
    const int*   cidx    = (const int*)d_in[2];
    const int*   sidx    = (const int*)d_in[3];
    float*       out     = (float*)d_out;

    if (ws_size < (size_t)WS_NEED) {
        hipMemsetAsync(out, 0, (size_t)out_size * sizeof(float), stream);
        hipLaunchKernelGGL(atomic_kernel, dim3(N_EDGES / 256), dim3(256), 0, stream,
                           vectors, rw, cidx, sidx, out);
        return;
    }

    char* ws = (char*)d_ws;
    int*          blkhist = (int*)(ws + WS_BLKHIST);
    int*          totals  = (int*)(ws + WS_TOTALS);
    int*          offsets = (int*)(ws + WS_OFFSETS);
    unsigned int* records = (unsigned int*)(ws + WS_REC);

    hipLaunchKernelGGL(hist_kernel,      dim3(HBLK),     dim3(256), 0, stream, cidx, sidx, blkhist);
    hipLaunchKernelGGL(scanA_kernel,     dim3(NBKT/128), dim3(128), 0, stream, blkhist, totals);
    hipLaunchKernelGGL(partition_kernel, dim3(HBLK),     dim3(256), 0, stream, cidx, sidx, blkhist, totals, records, offsets);
    hipLaunchKernelGGL(compute_kernel,   dim3(NBKT),     dim3(256), 0, stream, records, offsets, totals, vectors, rw, out);
}

// Round 20
// 145.470 us; speedup vs baseline: 1.3337x; 1.0094x over previous
//
#include <hip/hip_runtime.h>
#include <math.h>

#define N_EDGES     1048576
#define NBKT        4096         // bucket = seg >> 5 (32 segs / bucket)
#define SEG_PER_BKT 32
#define N_BASIS     12
#define CAP         344          // per-bucket capacity (Poisson(256)+5.5sd; slow path kept)
#define PAY_SZ      (CAP * 7 + CAP / 8)   // j-padded: slot(j) = 7j + (j>>3)
#define HBLK        64           // hist/partition blocks (1024 threads each)
#define HEPB        (N_EDGES / HBLK)   // 16384 edges per block

// rec = (sl << 20) | eid   (sl = seg & 31, eid < 2^20)

// ---- workspace layout (5.03 MB) ----
#define WS_BLKHIST  0                          // int[HBLK][NBKT]  (1 MB)
#define WS_TOTALS   (HBLK * NBKT * 4)          // int[NBKT] (16 KB)
#define WS_OFFSETS  (WS_TOTALS + NBKT * 4)     // int[NBKT] (16 KB)
#define WS_REC      (WS_OFFSETS + NBKT * 4)    // u32[N_EDGES] (4 MB)
#define WS_NEED     (WS_REC + (size_t)N_EDGES * 4)

__device__ __forceinline__ int pslot(int j) { return j * 7 + (j >> 3); }

__device__ __forceinline__ void compute_edge(float x, float y, float z,
                                             float* __restrict__ ph,   // 12, scaled by NORM/r
                                             float* __restrict__ sh)   // 16
{
    const float r2    = fmaf(x, x, fmaf(y, y, z * z)) + 1e-12f;
    const float inv_r = rsqrtf(r2);
    const float r     = r2 * inv_r;
    x *= inv_r; y *= inv_r; z *= inv_r;

    const float t = 0.6283185307179586f * r;   // pi/5 * r
    float s1, c1;
    __sincosf(t, &s1, &c1);
    const float twoc = 2.0f * c1;
    const float scale = 0.17677669529663687f * inv_r;  // (1/sqrt(32)) / r
    float skm1 = 0.0f, sk = s1;
    #pragma unroll
    for (int b = 0; b < N_BASIS; ++b) {
        ph[b] = sk * scale;
        const float nxt = fmaf(twoc, sk, -skm1);
        skm1 = sk; sk = nxt;
    }

    const float x2 = x * x, y2 = y * y, z2 = z * z;
    sh[0]  = 0.28209479177387814f;
    sh[1]  = 0.4886025119029199f * y;
    sh[2]  = 0.4886025119029199f * z;
    sh[3]  = 0.4886025119029199f * x;
    sh[4]  = 1.0925484305920792f * x * y;
    sh[5]  = 1.0925484305920792f * y * z;
    sh[6]  = 0.31539156525252005f * (3.0f * z2 - 1.0f);
    sh[7]  = 1.0925484305920792f * x * z;
    sh[8]  = 0.5462742152960396f * (x2 - y2);
    sh[9]  = 0.5900435899266435f * y * (3.0f * x2 - y2);
    sh[10] = 2.890611442640554f  * x * y * z;
    sh[11] = 0.4570457994644658f * y * (5.0f * z2 - 1.0f);
    sh[12] = 0.3731763325901154f * (5.0f * z2 * z - 3.0f * z);
    sh[13] = 0.4570457994644658f * x * (5.0f * z2 - 1.0f);
    sh[14] = 1.445305721320277f  * z * (x2 - y2);
    sh[15] = 0.5900435899266435f * x * (x2 - y2);
}

// ---------- 1: per-block histogram (1024 thr; int4 index loads; LDS only) ----------
__global__ __launch_bounds__(1024) void hist_kernel(
    const int* __restrict__ cidx, const int* __restrict__ sidx,
    int* __restrict__ blkhist)
{
    __shared__ int h[NBKT];                    // 16 KB
    const int t = threadIdx.x;
    #pragma unroll
    for (int i = t; i < NBKT; i += 1024) h[i] = 0;
    __syncthreads();
    const int base4 = blockIdx.x * (HEPB / 4);
    #pragma unroll
    for (int k = 0; k < HEPB / 4096; ++k) {    // 4 iterations of int4
        const int e4 = base4 + k * 1024 + t;
        const int4 c = ((const int4*)cidx)[e4];
        const int4 s = ((const int4*)sidx)[e4];
        atomicAdd(&h[((c.x << 2) | s.x) >> 5], 1);
        atomicAdd(&h[((c.y << 2) | s.y) >> 5], 1);
        atomicAdd(&h[((c.z << 2) | s.z) >> 5], 1);
        atomicAdd(&h[((c.w << 2) | s.w) >> 5], 1);
    }
    __syncthreads();
    #pragma unroll
    for (int i = t; i < NBKT; i += 1024)
        blkhist[blockIdx.x * NBKT + i] = h[i];
}

// ---------- 2: per-bucket exclusive scan over the 64 hist rows (8-wide batches) ----------
__global__ __launch_bounds__(128) void scanA_kernel(
    int* __restrict__ blkhist, int* __restrict__ totals)
{
    const int bkt = blockIdx.x * 128 + threadIdx.x;   // 4096 threads, 32 blocks
    int run = 0;
    for (int blk0 = 0; blk0 < HBLK; blk0 += 8) {
        int v[8];
        #pragma unroll
        for (int u = 0; u < 8; ++u)
            v[u] = blkhist[(blk0 + u) * NBKT + bkt];  // 8 loads in flight
        #pragma unroll
        for (int u = 0; u < 8; ++u) {
            blkhist[(blk0 + u) * NBKT + bkt] = run;   // exclusive within bucket
            run += v[u];
        }
    }
    totals[bkt] = run;
}

// ---------- 3: partition (1024 thr; fused offsets-scan; int4 index loads) ----------
__global__ __launch_bounds__(1024) void partition_kernel(
    const int* __restrict__ cidx, const int* __restrict__ sidx,
    const int* __restrict__ blkhist, const int* __restrict__ totals,
    unsigned int* __restrict__ records, int* __restrict__ offsets_g)
{
    __shared__ int off_s[NBKT];                // 16 KB: offsets, then bases in-place
    __shared__ int lcnt[NBKT];                 // 16 KB
    __shared__ int tmp[1024];
    const int t  = threadIdx.x;
    const int me = blockIdx.x;

    // redundant exclusive scan of the 4096 totals (serial-4 + 1024-ladder)
    int loc[4];
    int s = 0;
    const int base4t = t * 4;
    #pragma unroll
    for (int k = 0; k < 4; ++k) { loc[k] = s; s += totals[base4t + k]; }
    tmp[t] = s;
    __syncthreads();
    #pragma unroll
    for (int d = 1; d < 1024; d <<= 1) {
        const int v = (t >= d) ? tmp[t - d] : 0;
        __syncthreads();
        tmp[t] += v;
        __syncthreads();
    }
    const int ex = tmp[t] - s;
    #pragma unroll
    for (int k = 0; k < 4; ++k) off_s[base4t + k] = ex + loc[k];
    __syncthreads();

    // block 0 publishes offsets for the compute kernel
    if (me == 0) {
        #pragma unroll
        for (int k = 0; k < 4; ++k) offsets_g[base4t + k] = off_s[base4t + k];
    }

    // in-place bases for this block + zero rank counters
    #pragma unroll
    for (int i = t; i < NBKT; i += 1024) {
        off_s[i] += blkhist[me * NBKT + i];
        lcnt[i] = 0;
    }
    __syncthreads();

    const int base  = me * HEPB;
    const int base4 = me * (HEPB / 4);
    #pragma unroll
    for (int k = 0; k < HEPB / 4096; ++k) {    // 4 iterations of int4
        const int e4 = base4 + k * 1024 + t;
        const int4 c = ((const int4*)cidx)[e4];
        const int4 s4 = ((const int4*)sidx)[e4];
        const int e0 = base + (k * 1024 + t) * 4;
        int segs[4];
        segs[0] = (c.x << 2) | s4.x;
        segs[1] = (c.y << 2) | s4.y;
        segs[2] = (c.z << 2) | s4.z;
        segs[3] = (c.w << 2) | s4.w;
        #pragma unroll
        for (int j = 0; j < 4; ++j) {
            const int seg = segs[j];
            const int bkt = seg >> 5;
            const int r = atomicAdd(&lcnt[bkt], 1);
            records[off_s[bkt] + r] = ((unsigned)(seg & 31) << 20) | (unsigned)(e0 + j);
        }
    }
}

// ---------- 4: compute — ph+sh shared via swizzled LDS; thin walk (frozen) ----------
__global__ __launch_bounds__(256) void compute_kernel(
    const unsigned int* __restrict__ records,
    const int* __restrict__ offsets, const int* __restrict__ counts,
    const float* __restrict__ vectors,
    const float* __restrict__ rw,    // (4,12,8)
    float* __restrict__ out)
{
    __shared__ float4 pay[PAY_SZ];             // 39.2 KB: per edge ph[12]+sh[16], j-padded
    __shared__ int shist[SEG_PER_BKT];
    __shared__ int soff[SEG_PER_BKT + 1];
    __shared__ int scur[SEG_PER_BKT];

    const int t = threadIdx.x;
    const int b = blockIdx.x;                  // 4096 buckets
    const int n = t & 7;                       // radial index owned by this lane
    const int g = t >> 3;                      // group 0..31; owns segment g

    const int off = offsets[b];
    const int cnt = counts[b];

    if (cnt > CAP) {
        // correctness-only slow path (P ~ 8e-5 per run)
        float Wn[4][N_BASIS];
        #pragma unroll
        for (int l = 0; l < 4; ++l)
            #pragma unroll
            for (int bb2 = 0; bb2 < N_BASIS; ++bb2)
                Wn[l][bb2] = rw[(l * N_BASIS + bb2) * 8 + n];
        float acc[16];
        #pragma unroll
        for (int L = 0; L < 16; ++L) acc[L] = 0.0f;
        for (int j = 0; j < cnt; ++j) {
            const unsigned rec = records[off + j];
            if ((int)(rec >> 20) != g) continue;
            const int eid = rec & 0xFFFFF;
            float ph[N_BASIS], sh[16];
            compute_edge(vectors[3*eid], vectors[3*eid+1], vectors[3*eid+2], ph, sh);
            float rad[4];
            #pragma unroll
            for (int l = 0; l < 4; ++l) {
                float a = 0.0f;
                #pragma unroll
                for (int bb2 = 0; bb2 < N_BASIS; ++bb2)
                    a = fmaf(ph[bb2], Wn[l][bb2], a);
                rad[l] = a;
            }
            #pragma unroll
            for (int L = 0; L < 16; ++L) {
                const int l = (L == 0) ? 0 : (L < 4) ? 1 : (L < 9) ? 2 : 3;
                acc[L] = fmaf(sh[L], rad[l], acc[L]);
            }
        }
        const int seg = b * SEG_PER_BKT + g;
        float* op = out + (size_t)(seg >> 2) * 512 + (seg & 3) * 8 + n;
        #pragma unroll
        for (int L = 0; L < 16; ++L) op[L * 32] = acc[L];
        return;
    }

    if (t < SEG_PER_BKT) shist[t] = 0;
    __syncthreads();

    // pass 1: load records (coalesced 4B), histogram by local segment
    unsigned recs[2];
    const int iters = (cnt + 255) >> 8;        // <= 2
    #pragma unroll
    for (int it = 0; it < 2; ++it) {
        const int i = it * 256 + t;
        if (it < iters && i < cnt) {
            recs[it] = records[off + i];
            atomicAdd(&shist[recs[it] >> 20], 1);
        }
    }
    __syncthreads();

    // barrier-free scan of 32 entries on wave 0
    if (t < SEG_PER_BKT) {
        const int h = shist[t];
        int v = h;
        #pragma unroll
        for (int d = 1; d < 32; d <<= 1) {
            const int u = __shfl_up(v, d, 32);
            if (t >= d) v += u;
        }
        soff[t] = v - h;
        scur[t] = v - h;
        if (t == 31) soff[32] = v;             // sentinel = cnt
    }
    __syncthreads();

    // pass 2: gather xyz (parallel) + compute_edge ONCE; store ph+sh to swizzled slot
    #pragma unroll
    for (int it = 0; it < 2; ++it) {
        const int i = it * 256 + t;
        if (it < iters && i < cnt) {
            const int sl  = recs[it] >> 20;
            const int eid = recs[it] & 0xFFFFF;
            const float x = vectors[3 * eid + 0];
            const float y = vectors[3 * eid + 1];
            const float z = vectors[3 * eid + 2];
            const int r = atomicAdd(&scur[sl], 1);
            float ph[N_BASIS], sh[16];
            compute_edge(x, y, z, ph, sh);
            float4* pp = &pay[pslot(r)];
            pp[0] = make_float4(ph[0], ph[1], ph[2], ph[3]);
            pp[1] = make_float4(ph[4], ph[5], ph[6], ph[7]);
            pp[2] = make_float4(ph[8], ph[9], ph[10], ph[11]);
            pp[3] = make_float4(sh[0], sh[1], sh[2], sh[3]);
            pp[4] = make_float4(sh[4], sh[5], sh[6], sh[7]);
            pp[5] = make_float4(sh[8], sh[9], sh[10], sh[11]);
            pp[6] = make_float4(sh[12], sh[13], sh[14], sh[15]);
        }
    }
    __syncthreads();

    // per-lane W slice
    float Wn[4][N_BASIS];
    #pragma unroll
    for (int l = 0; l < 4; ++l)
        #pragma unroll
        for (int bb2 = 0; bb2 < N_BASIS; ++bb2)
            Wn[l][bb2] = rw[(l * N_BASIS + bb2) * 8 + n];

    // thin walk: group g owns segment g; broadcast b128 reads; rad+acc only
    const int js = soff[g];
    const int je = soff[g + 1];

    float acc[16];
    #pragma unroll
    for (int L = 0; L < 16; ++L) acc[L] = 0.0f;

    for (int j = js; j < je; ++j) {
        const float4* pp = &pay[pslot(j)];
        const float4 p0 = pp[0], p1 = pp[1], p2 = pp[2];
        const float4 s0 = pp[3], s1 = pp[4], s2 = pp[5], s3 = pp[6];

        float rad[4];
        #pragma unroll
        for (int l = 0; l < 4; ++l) {
            float a =      p0.x * Wn[l][0];
            a = fmaf(p0.y, Wn[l][1],  a);
            a = fmaf(p0.z, Wn[l][2],  a);
            a = fmaf(p0.w, Wn[l][3],  a);
            a = fmaf(p1.x, Wn[l][4],  a);
            a = fmaf(p1.y, Wn[l][5],  a);
            a = fmaf(p1.z, Wn[l][6],  a);
            a = fmaf(p1.w, Wn[l][7],  a);
            a = fmaf(p2.x, Wn[l][8],  a);
            a = fmaf(p2.y, Wn[l][9],  a);
            a = fmaf(p2.z, Wn[l][10], a);
            a = fmaf(p2.w, Wn[l][11], a);
            rad[l] = a;
        }
        acc[0]  = fmaf(s0.x, rad[0], acc[0]);
        acc[1]  = fmaf(s0.y, rad[1], acc[1]);
        acc[2]  = fmaf(s0.z, rad[1], acc[2]);
        acc[3]  = fmaf(s0.w, rad[1], acc[3]);
        acc[4]  = fmaf(s1.x, rad[2], acc[4]);
        acc[5]  = fmaf(s1.y, rad[2], acc[5]);
        acc[6]  = fmaf(s1.z, rad[2], acc[6]);
        acc[7]  = fmaf(s1.w, rad[2], acc[7]);
        acc[8]  = fmaf(s2.x, rad[2], acc[8]);
        acc[9]  = fmaf(s2.y, rad[3], acc[9]);
        acc[10] = fmaf(s2.z, rad[3], acc[10]);
        acc[11] = fmaf(s2.w, rad[3], acc[11]);
        acc[12] = fmaf(s3.x, rad[3], acc[12]);
        acc[13] = fmaf(s3.y, rad[3], acc[13]);
        acc[14] = fmaf(s3.z, rad[3], acc[14]);
        acc[15] = fmaf(s3.w, rad[3], acc[15]);
    }

    // unconditional flush (covers empty segments: acc stays zero)
    const int seg = b * SEG_PER_BKT + g;
    float* op = out + (size_t)(seg >> 2) * 512 + (seg & 3) * 8 + n;
    #pragma unroll
    for (int L = 0; L < 16; ++L) op[L * 32] = acc[L];
}

// ---------- fallback: atomic kernel (used only if ws too small) ----------
__global__ __launch_bounds__(256) void atomic_kernel(
    const float* __restrict__ vectors, const float* __restrict__ rw,
    const int* __restrict__ cidx, const int* __restrict__ sidx,
    float* __restrict__ out)
{
    const int e = blockIdx.x * 256 + threadIdx.x;
    if (e >= N_EDGES) return;
    float ph[N_BASIS], sh[16];
    compute_edge(vectors[3*e], vectors[3*e+1], vectors[3*e+2], ph, sh);
    float* op = out + (size_t)cidx[e] * 512 + sidx[e] * 8;
    for (int l = 0; l < 4; ++l) {
        const int L0 = l * l;
        const int ml = 2 * l + 1;
        for (int nn = 0; nn < 8; ++nn) {
            float rad = 0.0f;
            for (int bb2 = 0; bb2 < N_BASIS; ++bb2)
                rad = fmaf(ph[bb2], rw[(l * N_BASIS + bb2) * 8 + nn], rad);
            for (int mm = 0; mm < ml; ++mm)
                atomicAdd(op + (L0 + mm) * 32 + nn, sh[L0 + mm] * rad);
        }
    }
}

extern "C" void kernel_launch(void* const* d_in, const int* in_sizes, int n_in,
                              void* d_out, int out_size, void* d_ws, size_t ws_size,
                              hipStream_t stream) {
    const float* vectors = (const float*)d_in[0];
    const float* rw      = (const float*)d_in[1];
    const int*   cidx    = (const int*)d_in[2];
    const int*   sidx    = (const int*)d_in[3];
    float*       out     = (float*)d_out;

    if (ws_size < (size_t)WS_NEED) {
        hipMemsetAsync(out, 0, (size_t)out_size * sizeof(float), stream);
        hipLaunchKernelGGL(atomic_kernel, dim3(N_EDGES / 256), dim3(256), 0, stream,
                           vectors, rw, cidx, sidx, out);
        return;
    }

    char* ws = (char*)d_ws;
    int*          blkhist = (int*)(ws + WS_BLKHIST);
    int*          totals  = (int*)(ws + WS_TOTALS);
    int*          offsets = (int*)(ws + WS_OFFSETS);
    unsigned int* records = (unsigned int*)(ws + WS_REC);

    hipLaunchKernelGGL(hist_kernel,      dim3(HBLK),     dim3(1024), 0, stream, cidx, sidx, blkhist);
    hipLaunchKernelGGL(scanA_kernel,     dim3(NBKT/128), dim3(128),  0, stream, blkhist, totals);
    hipLaunchKernelGGL(partition_kernel, dim3(HBLK),     dim3(1024), 0, stream, cidx, sidx, blkhist, totals, records, offsets);
    hipLaunchKernelGGL(compute_kernel,   dim3(NBKT),     dim3(256),  0, stream, records, offsets, totals, vectors, rw, out);
}